// Round 1
// baseline (630.653 us; speedup 1.0000x reference)
//
#include <hip/hip_runtime.h>
#include <hip/hip_bf16.h>

#define RELS 8
#define INF_ 64
#define HDD 128
#define NH 4

typedef __attribute__((ext_vector_type(8))) short bf16x8;
typedef __attribute__((ext_vector_type(4))) float f32x4;
typedef unsigned short u16;

__device__ __forceinline__ u16 f2b(float v){
  union { float f; unsigned u; } x; x.f = v;
  unsigned r = x.u + 0x7fffu + ((x.u >> 16) & 1u);
  return (u16)(r >> 16);
}
__device__ __forceinline__ float b2f(u16 h){
  union { unsigned u; float f; } x; x.u = ((unsigned)h) << 16; return x.f;
}

// ---- prep: combined transposed weights (bf16) + combined bias ----
__global__ void k_prep_w(const float* __restrict__ wsrc, const float* __restrict__ wqual,
                         const float* __restrict__ bsrc, const float* __restrict__ bqual,
                         u16* __restrict__ Wt, float* __restrict__ biasc){
  int g = blockIdx.x*256 + threadIdx.x;
  if (g < RELS*HDD*HDD){
    int r = g >> 14, rem = g & 16383, n = rem >> 7, k = rem & 127;
    // Wt[r][n][k] = W_combined[k][n]; k<64 from fc_src_w, else fc_qual_w
    float v = (k < 64) ? wsrc[r*8192 + k*128 + n] : wqual[r*8192 + (k-64)*128 + n];
    Wt[g] = f2b(v);
  } else {
    int b = g - RELS*HDD*HDD;
    if (b < RELS*HDD) biasc[b] = bsrc[b] + bqual[b];
  }
}

// ---- prep: fp32 -> bf16 copies of feat and quality_emb ----
__global__ void k_prep_feat(const float* __restrict__ feat, const float* __restrict__ qual,
                            u16* __restrict__ featb, u16* __restrict__ qualb, int total){
  int g = (blockIdx.x*256 + threadIdx.x) * 8;
  const float* sp; u16* dp;
  if (g < total){ sp = feat; dp = featb; }
  else { g -= total; if (g >= total) return; sp = qual; dp = qualb; }
  float4 a = *(const float4*)(sp + g);
  float4 b = *(const float4*)(sp + g + 4);
  union { u16 h[8]; uint4 v; } o;
  o.h[0]=f2b(a.x); o.h[1]=f2b(a.y); o.h[2]=f2b(a.z); o.h[3]=f2b(a.w);
  o.h[4]=f2b(b.x); o.h[5]=f2b(b.y); o.h[6]=f2b(b.z); o.h[7]=f2b(b.w);
  *(uint4*)(dp + g) = o.v;
}

// ---- histograms: degree by dst, counts by relation ----
__global__ void k_hist(const int* __restrict__ dst, const int* __restrict__ rt,
                       int* __restrict__ deg, int* __restrict__ rcnt, int E){
  __shared__ int lh[RELS];
  int t = threadIdx.x;
  if (t < RELS) lh[t] = 0;
  __syncthreads();
  int e = blockIdx.x*256 + t;
  if (e < E){
    atomicAdd(&deg[dst[e]], 1);
    atomicAdd(&lh[rt[e]], 1);
  }
  __syncthreads();
  if (t < RELS && lh[t]) atomicAdd(&rcnt[t], lh[t]);
}

// ---- 3-phase exclusive scan over deg[N] -> offD ----
__global__ void k_scan_a(const int* __restrict__ deg, int* __restrict__ offD,
                         int* __restrict__ bsums, int N){
  __shared__ int s[256];
  int t = threadIdx.x, i = blockIdx.x*256 + t;
  int v = (i < N) ? deg[i] : 0;
  s[t] = v; __syncthreads();
  for (int off=1; off<256; off<<=1){
    int x = (t >= off) ? s[t-off] : 0;
    __syncthreads();
    s[t] += x;
    __syncthreads();
  }
  if (i < N) offD[i] = s[t] - v;
  if (t == 255) bsums[blockIdx.x] = s[255];
}

__global__ void k_scan_b(const int* __restrict__ bsums, int* __restrict__ bsums_sc,
                         int* __restrict__ offD, const int* __restrict__ rcnt,
                         int* __restrict__ roff, int* __restrict__ rcur,
                         int NBLK, int N){
  __shared__ int s[512];
  int t = threadIdx.x;
  int v = (t < NBLK) ? bsums[t] : 0;
  s[t] = v; __syncthreads();
  for (int off=1; off<512; off<<=1){
    int x = (t >= off) ? s[t-off] : 0;
    __syncthreads();
    s[t] += x;
    __syncthreads();
  }
  if (t < NBLK) bsums_sc[t] = s[t] - v;
  if (t == NBLK-1) offD[N] = s[t];
  if (t == 0){
    int a = 0;
    for (int r=0;r<RELS;r++){ roff[r]=a; rcur[r]=a; a += rcnt[r]; }
    roff[RELS] = a;
  }
}

__global__ void k_scan_c(int* __restrict__ offD, const int* __restrict__ bsums_sc, int N){
  int i = blockIdx.x*256 + threadIdx.x;
  if (i < N) offD[i] += bsums_sc[i >> 8];
}

// ---- scatter into dst-sorted permD and rel-sorted permR ----
__global__ void k_scatter(const int* __restrict__ dst, const int* __restrict__ rt,
                          const int* __restrict__ offD, int* __restrict__ curD,
                          int* __restrict__ rcur,
                          int* __restrict__ permD, int* __restrict__ permR, int E){
  __shared__ int lh[RELS], lb[RELS];
  int t = threadIdx.x;
  if (t < RELS) lh[t] = 0;
  __syncthreads();
  int e = blockIdx.x*256 + t;
  int r = 0, rank = 0;
  if (e < E){
    int d = dst[e];
    int pd = offD[d] + atomicAdd(&curD[d], 1);
    permD[pd] = e;
    r = rt[e];
    rank = atomicAdd(&lh[r], 1);
  }
  __syncthreads();
  if (t < RELS && lh[t] > 0) lb[t] = atomicAdd(&rcur[t], lh[t]);
  __syncthreads();
  if (e < E) permR[lb[r] + rank] = e;
}

// ---- fused projection + leaky_relu + attn dot -> score[E,4], MFMA ----
__global__ __launch_bounds__(256) void k_score(
    const u16* __restrict__ featb, const u16* __restrict__ qualb,
    const u16* __restrict__ Wt, const float* __restrict__ biasc,
    const float* __restrict__ attn,
    const int* __restrict__ src, const int* __restrict__ nidp,
    const int* __restrict__ permR, const int* __restrict__ roff,
    float* __restrict__ score){
  __shared__ u16 As[64][136];
  __shared__ u16 Bs[128][136];
  __shared__ int eids[64];
  __shared__ int sseg[3];
  int t = threadIdx.x;
  if (t == 0){
    int acc = 0, r = -1, base = 0, cnt = 0, bid = blockIdx.x;
    for (int rr=0; rr<RELS; rr++){
      int c = roff[rr+1] - roff[rr];
      int nb = (c + 63) >> 6;
      if (bid < acc + nb){
        int ch = bid - acc;
        r = rr; base = roff[rr] + ch*64; cnt = min(64, c - ch*64);
        break;
      }
      acc += nb;
    }
    sseg[0]=r; sseg[1]=base; sseg[2]=cnt;
  }
  __syncthreads();
  int r = sseg[0];
  if (r < 0) return;
  int base = sseg[1], cnt = sseg[2];

  // stage A: 64 edges x 128 bf16 (concat feat[src], qual[nid]); 4 threads/edge
  int mloc = t >> 2, part = t & 3;
  if (mloc < cnt){
    int e = permR[base + mloc];
    if (part == 0) eids[mloc] = e;
    const u16* rowp = (part < 2) ? (featb + (long long)src[e]*64)
                                 : (qualb + (long long)nidp[e]*64);
    const uint4* pv = (const uint4*)(rowp + (part & 1)*32);
    uint4 v0 = pv[0], v1 = pv[1], v2 = pv[2], v3 = pv[3];
    uint4* q = (uint4*)&As[mloc][part*32];
    q[0]=v0; q[1]=v1; q[2]=v2; q[3]=v3;
  } else {
    if (part == 0) eids[mloc] = -1;
    uint4 z = {0,0,0,0};
    uint4* q = (uint4*)&As[mloc][part*32];
    q[0]=z; q[1]=z; q[2]=z; q[3]=z;
  }
  // stage B: Wt[r] (n-major [128][128] bf16) -> Bs[n][k], padded rows
  const uint4* wg = (const uint4*)(Wt + r*16384);
  #pragma unroll
  for (int i=0;i<8;i++){
    int c = i*256 + t;           // 2048 chunks of 8 bf16
    uint4 v = wg[c];
    int n = c >> 4, k = (c & 15) * 8;
    *(uint4*)&Bs[n][k] = v;
  }
  __syncthreads();

  int lane = t & 63, w = t >> 6;
  int lr = lane & 15, lq = lane >> 4;
  int arow = w*16 + lr;
  f32x4 acc[8];
  #pragma unroll
  for (int nt=0; nt<8; nt++) acc[nt] = (f32x4){0.f,0.f,0.f,0.f};
  #pragma unroll
  for (int kt=0; kt<4; kt++){
    int k = kt*32 + lq*8;
    bf16x8 af = *(const bf16x8*)&As[arow][k];
    #pragma unroll
    for (int nt=0; nt<8; nt++){
      bf16x8 bf = *(const bf16x8*)&Bs[nt*16 + lr][k];
      acc[nt] = __builtin_amdgcn_mfma_f32_16x16x32_bf16(af, bf, acc[nt], 0, 0, 0);
    }
  }
  // epilogue: + bias, leaky_relu, * attn, reduce 32-col heads
  float sh[NH][4];
  #pragma unroll
  for (int h=0; h<NH; h++)
    #pragma unroll
    for (int i=0; i<4; i++) sh[h][i] = 0.f;
  #pragma unroll
  for (int nt=0; nt<8; nt++){
    int col = nt*16 + lr;
    float av = attn[r*128 + col];
    float bv = biasc[r*128 + col];
    int h = nt >> 1;
    #pragma unroll
    for (int i=0; i<4; i++){
      float x = acc[nt][i] + bv;
      x = (x > 0.f) ? x : 0.2f*x;
      sh[h][i] += x*av;
    }
  }
  #pragma unroll
  for (int h=0; h<NH; h++)
    #pragma unroll
    for (int i=0; i<4; i++){
      float v = sh[h][i];
      v += __shfl_xor(v, 1);
      v += __shfl_xor(v, 2);
      v += __shfl_xor(v, 4);
      v += __shfl_xor(v, 8);
      sh[h][i] = v;
    }
  if (lr == 0){
    #pragma unroll
    for (int i=0; i<4; i++){
      int m = w*16 + lq*4 + i;
      int e = eids[m];
      if (e >= 0){
        float4 sv = { sh[0][i], sh[1][i], sh[2][i], sh[3][i] };
        *(float4*)&score[(long long)e*4] = sv;
      }
    }
  }
}

// ---- per-node softmax + weighted aggregation; wave per node, lane = feat dim ----
__global__ __launch_bounds__(256) void k_aggregate(
    const int* __restrict__ offD, const int* __restrict__ permD,
    const int* __restrict__ src, const float* __restrict__ score,
    const u16* __restrict__ featb, float* __restrict__ out, int N){
  int node = blockIdx.x*4 + (threadIdx.x >> 6);
  int lane = threadIdx.x & 63;
  if (node >= N) return;
  int s0 = offD[node], s1 = offD[node+1];
  float a0=0.f, a1=0.f, a2=0.f, a3=0.f;
  if (s1 > s0){
    float m0=-1e30f, m1=-1e30f, m2=-1e30f, m3=-1e30f;
    for (int j=s0; j<s1; j++){
      int e = permD[j];
      float4 sc = *(const float4*)&score[(long long)e*4];
      m0=fmaxf(m0,sc.x); m1=fmaxf(m1,sc.y); m2=fmaxf(m2,sc.z); m3=fmaxf(m3,sc.w);
    }
    float d0=0.f,d1=0.f,d2=0.f,d3=0.f;
    for (int j=s0; j<s1; j++){
      int e = permD[j];
      float4 sc = *(const float4*)&score[(long long)e*4];
      d0+=__expf(sc.x-m0); d1+=__expf(sc.y-m1); d2+=__expf(sc.z-m2); d3+=__expf(sc.w-m3);
    }
    float i0=1.f/d0, i1=1.f/d1, i2=1.f/d2, i3=1.f/d3;
    for (int j=s0; j<s1; j++){
      int e = permD[j];
      float4 sc = *(const float4*)&score[(long long)e*4];
      float fv = b2f(featb[(long long)src[e]*64 + lane]);
      a0 += __expf(sc.x-m0)*i0*fv;
      a1 += __expf(sc.y-m1)*i1*fv;
      a2 += __expf(sc.z-m2)*i2*fv;
      a3 += __expf(sc.w-m3)*i3*fv;
    }
  }
  float* op = out + (long long)node*256;
  op[lane]       = a0;
  op[64 + lane]  = a1;
  op[128 + lane] = a2;
  op[192 + lane] = a3;
}

extern "C" void kernel_launch(void* const* d_in, const int* in_sizes, int n_in,
                              void* d_out, int out_size, void* d_ws, size_t ws_size,
                              hipStream_t stream) {
  const float* feat  = (const float*)d_in[0];
  const float* qual  = (const float*)d_in[1];
  const float* wsrc  = (const float*)d_in[2];
  const float* bsrc  = (const float*)d_in[3];
  const float* wqual = (const float*)d_in[4];
  const float* bqual = (const float*)d_in[5];
  const float* attn  = (const float*)d_in[6];
  const int* src = (const int*)d_in[7];
  const int* dst = (const int*)d_in[8];
  const int* rt  = (const int*)d_in[9];
  const int* nid = (const int*)d_in[10];
  const int E = in_sizes[7];
  const int N = in_sizes[0] / 64;
  float* out = (float*)d_out;

  char* p = (char*)d_ws;
  auto alloc = [&](size_t bytes) -> void* {
    void* q = (void*)p;
    p += (bytes + 255) & ~(size_t)255;
    return q;
  };
  float* score   = (float*)alloc((size_t)E*4*4);
  u16*  featb    = (u16*)  alloc((size_t)N*64*2);
  u16*  qualb    = (u16*)  alloc((size_t)N*64*2);
  u16*  Wt       = (u16*)  alloc((size_t)RELS*HDD*HDD*2);
  float* biasc   = (float*)alloc((size_t)RELS*HDD*4);
  int*  permD    = (int*)  alloc((size_t)E*4);
  int*  permR    = (int*)  alloc((size_t)E*4);
  int*  offD     = (int*)  alloc((size_t)(N+1)*4);
  int*  bsums    = (int*)  alloc(4096);
  int*  bsums_sc = (int*)  alloc(4096);
  char* zbase = p;
  int*  deg      = (int*)  alloc((size_t)N*4);
  int*  curD     = (int*)  alloc((size_t)N*4);
  int*  rcnt     = (int*)  alloc(32);
  int*  roff     = (int*)  alloc(64);
  int*  rcur     = (int*)  alloc(32);
  size_t zbytes = (size_t)(p - zbase);

  hipMemsetAsync(zbase, 0, zbytes, stream);

  // prep
  {
    int totw = RELS*HDD*HDD + RELS*HDD;
    k_prep_w<<<(totw + 255)/256, 256, 0, stream>>>(wsrc, wqual, bsrc, bqual, Wt, biasc);
    int total = N*64;
    int nthr = (2*total)/8;
    k_prep_feat<<<(nthr + 255)/256, 256, 0, stream>>>(feat, qual, featb, qualb, total);
  }
  // histogram + scan + scatter
  int EB = (E + 255)/256;
  k_hist<<<EB, 256, 0, stream>>>(dst, rt, deg, rcnt, E);
  int NBLK = (N + 255)/256;
  k_scan_a<<<NBLK, 256, 0, stream>>>(deg, offD, bsums, N);
  k_scan_b<<<1, 512, 0, stream>>>(bsums, bsums_sc, offD, rcnt, roff, rcur, NBLK, N);
  k_scan_c<<<NBLK, 256, 0, stream>>>(offD, bsums_sc, N);
  k_scatter<<<EB, 256, 0, stream>>>(dst, rt, offD, curD, rcur, permD, permR, E);
  // fused score
  int NBS = (E + 63)/64 + RELS;
  k_score<<<NBS, 256, 0, stream>>>(featb, qualb, Wt, biasc, attn, src, nid, permR, roff, score);
  // softmax + aggregate
  k_aggregate<<<(N + 3)/4, 256, 0, stream>>>(offD, permD, src, score, featb, out, N);
}

// Round 2
// 458.275 us; speedup vs baseline: 1.3761x; 1.3761x over previous
//
#include <hip/hip_runtime.h>
#include <hip/hip_bf16.h>

#define RELS 8
#define INF_ 64
#define HDD 128
#define NH 4

typedef __attribute__((ext_vector_type(8))) short bf16x8;
typedef __attribute__((ext_vector_type(4))) float f32x4;
typedef unsigned short u16;

__device__ __forceinline__ u16 f2b(float v){
  union { float f; unsigned u; } x; x.f = v;
  unsigned r = x.u + 0x7fffu + ((x.u >> 16) & 1u);
  return (u16)(r >> 16);
}
__device__ __forceinline__ float b2f(u16 h){
  union { unsigned u; float f; } x; x.u = ((unsigned)h) << 16; return x.f;
}

// ---- prep: combined transposed weights (bf16) + combined bias ----
__global__ void k_prep_w(const float* __restrict__ wsrc, const float* __restrict__ wqual,
                         const float* __restrict__ bsrc, const float* __restrict__ bqual,
                         u16* __restrict__ Wt, float* __restrict__ biasc){
  int g = blockIdx.x*256 + threadIdx.x;
  if (g < RELS*HDD*HDD){
    int r = g >> 14, rem = g & 16383, n = rem >> 7, k = rem & 127;
    float v = (k < 64) ? wsrc[r*8192 + k*128 + n] : wqual[r*8192 + (k-64)*128 + n];
    Wt[g] = f2b(v);
  } else {
    int b = g - RELS*HDD*HDD;
    if (b < RELS*HDD) biasc[b] = bsrc[b] + bqual[b];
  }
}

// ---- prep: fp32 -> bf16 copies of feat and quality_emb ----
__global__ void k_prep_feat(const float* __restrict__ feat, const float* __restrict__ qual,
                            u16* __restrict__ featb, u16* __restrict__ qualb, int total){
  int g = (blockIdx.x*256 + threadIdx.x) * 8;
  const float* sp; u16* dp;
  if (g < total){ sp = feat; dp = featb; }
  else { g -= total; if (g >= total) return; sp = qual; dp = qualb; }
  float4 a = *(const float4*)(sp + g);
  float4 b = *(const float4*)(sp + g + 4);
  union { u16 h[8]; uint4 v; } o;
  o.h[0]=f2b(a.x); o.h[1]=f2b(a.y); o.h[2]=f2b(a.z); o.h[3]=f2b(a.w);
  o.h[4]=f2b(b.x); o.h[5]=f2b(b.y); o.h[6]=f2b(b.z); o.h[7]=f2b(b.w);
  *(uint4*)(dp + g) = o.v;
}

// ---- histograms: degree by dst, counts by relation ----
__global__ void k_hist(const int* __restrict__ dst, const int* __restrict__ rt,
                       int* __restrict__ deg, int* __restrict__ rcnt, int E){
  __shared__ int lh[RELS];
  int t = threadIdx.x;
  if (t < RELS) lh[t] = 0;
  __syncthreads();
  int e = blockIdx.x*256 + t;
  if (e < E){
    atomicAdd(&deg[dst[e]], 1);
    atomicAdd(&lh[rt[e]], 1);
  }
  __syncthreads();
  if (t < RELS && lh[t]) atomicAdd(&rcnt[t], lh[t]);
}

// ---- 3-phase exclusive scan over deg[N] -> offD ----
__global__ void k_scan_a(const int* __restrict__ deg, int* __restrict__ offD,
                         int* __restrict__ bsums, int N){
  __shared__ int s[256];
  int t = threadIdx.x, i = blockIdx.x*256 + t;
  int v = (i < N) ? deg[i] : 0;
  s[t] = v; __syncthreads();
  for (int off=1; off<256; off<<=1){
    int x = (t >= off) ? s[t-off] : 0;
    __syncthreads();
    s[t] += x;
    __syncthreads();
  }
  if (i < N) offD[i] = s[t] - v;
  if (t == 255) bsums[blockIdx.x] = s[255];
}

__global__ void k_scan_b(const int* __restrict__ bsums, int* __restrict__ bsums_sc,
                         int* __restrict__ offD, const int* __restrict__ rcnt,
                         int* __restrict__ roff, int* __restrict__ rcur,
                         int NBLK, int N){
  __shared__ int s[512];
  int t = threadIdx.x;
  int v = (t < NBLK) ? bsums[t] : 0;
  s[t] = v; __syncthreads();
  for (int off=1; off<512; off<<=1){
    int x = (t >= off) ? s[t-off] : 0;
    __syncthreads();
    s[t] += x;
    __syncthreads();
  }
  if (t < NBLK) bsums_sc[t] = s[t] - v;
  if (t == NBLK-1) offD[N] = s[t];
  if (t == 0){
    int a = 0;
    for (int r=0;r<RELS;r++){ roff[r]=a; rcur[r]=a; a += rcnt[r]; }
    roff[RELS] = a;
  }
}

__global__ void k_scan_c(int* __restrict__ offD, const int* __restrict__ bsums_sc, int N){
  int i = blockIdx.x*256 + threadIdx.x;
  if (i < N) offD[i] += bsums_sc[i >> 8];
}

// ---- scatter: dst-sorted positions (with gathered src + inverse perm) and rel-sorted permR ----
__global__ void k_scatter(const int* __restrict__ dst, const int* __restrict__ rt,
                          const int* __restrict__ src,
                          const int* __restrict__ offD, int* __restrict__ curD,
                          int* __restrict__ rcur,
                          int* __restrict__ srcD, int* __restrict__ posD,
                          int* __restrict__ permR, int E){
  __shared__ int lh[RELS], lb[RELS];
  int t = threadIdx.x;
  if (t < RELS) lh[t] = 0;
  __syncthreads();
  int e = blockIdx.x*256 + t;
  int r = 0, rank = 0;
  if (e < E){
    int d = dst[e];
    int pd = offD[d] + atomicAdd(&curD[d], 1);
    srcD[pd] = src[e];
    posD[e] = pd;
    r = rt[e];
    rank = atomicAdd(&lh[r], 1);
  }
  __syncthreads();
  if (t < RELS && lh[t] > 0) lb[t] = atomicAdd(&rcur[t], lh[t]);
  __syncthreads();
  if (e < E) permR[lb[r] + rank] = e;
}

// ---- fused projection + leaky_relu + attn dot -> scoreD[posD[e],4], MFMA ----
__global__ __launch_bounds__(256) void k_score(
    const u16* __restrict__ featb, const u16* __restrict__ qualb,
    const u16* __restrict__ Wt, const float* __restrict__ biasc,
    const float* __restrict__ attn,
    const int* __restrict__ src, const int* __restrict__ nidp,
    const int* __restrict__ permR, const int* __restrict__ roff,
    const int* __restrict__ posD,
    float* __restrict__ scoreD){
  __shared__ u16 As[64][136];
  __shared__ u16 Bs[128][136];
  __shared__ int eids[64];
  __shared__ int sseg[3];
  int t = threadIdx.x;
  if (t == 0){
    int acc = 0, r = -1, base = 0, cnt = 0, bid = blockIdx.x;
    for (int rr=0; rr<RELS; rr++){
      int c = roff[rr+1] - roff[rr];
      int nb = (c + 63) >> 6;
      if (bid < acc + nb){
        int ch = bid - acc;
        r = rr; base = roff[rr] + ch*64; cnt = min(64, c - ch*64);
        break;
      }
      acc += nb;
    }
    sseg[0]=r; sseg[1]=base; sseg[2]=cnt;
  }
  __syncthreads();
  int r = sseg[0];
  if (r < 0) return;
  int base = sseg[1], cnt = sseg[2];

  // stage A: 64 edges x 128 bf16 (concat feat[src], qual[nid]); 4 threads/edge
  int mloc = t >> 2, part = t & 3;
  if (mloc < cnt){
    int e = permR[base + mloc];
    if (part == 0) eids[mloc] = e;
    const u16* rowp = (part < 2) ? (featb + (long long)src[e]*64)
                                 : (qualb + (long long)nidp[e]*64);
    const uint4* pv = (const uint4*)(rowp + (part & 1)*32);
    uint4 v0 = pv[0], v1 = pv[1], v2 = pv[2], v3 = pv[3];
    uint4* q = (uint4*)&As[mloc][part*32];
    q[0]=v0; q[1]=v1; q[2]=v2; q[3]=v3;
  } else {
    if (part == 0) eids[mloc] = -1;
    uint4 z = {0,0,0,0};
    uint4* q = (uint4*)&As[mloc][part*32];
    q[0]=z; q[1]=z; q[2]=z; q[3]=z;
  }
  // stage B: Wt[r] (n-major [128][128] bf16) -> Bs[n][k], padded rows
  const uint4* wg = (const uint4*)(Wt + r*16384);
  #pragma unroll
  for (int i=0;i<8;i++){
    int c = i*256 + t;
    uint4 v = wg[c];
    int n = c >> 4, k = (c & 15) * 8;
    *(uint4*)&Bs[n][k] = v;
  }
  __syncthreads();

  int lane = t & 63, w = t >> 6;
  int lr = lane & 15, lq = lane >> 4;
  int arow = w*16 + lr;
  f32x4 acc[8];
  #pragma unroll
  for (int nt=0; nt<8; nt++) acc[nt] = (f32x4){0.f,0.f,0.f,0.f};
  #pragma unroll
  for (int kt=0; kt<4; kt++){
    int k = kt*32 + lq*8;
    bf16x8 af = *(const bf16x8*)&As[arow][k];
    #pragma unroll
    for (int nt=0; nt<8; nt++){
      bf16x8 bf = *(const bf16x8*)&Bs[nt*16 + lr][k];
      acc[nt] = __builtin_amdgcn_mfma_f32_16x16x32_bf16(af, bf, acc[nt], 0, 0, 0);
    }
  }
  // epilogue: + bias, leaky_relu, * attn, reduce 32-col heads
  float sh[NH][4];
  #pragma unroll
  for (int h=0; h<NH; h++)
    #pragma unroll
    for (int i=0; i<4; i++) sh[h][i] = 0.f;
  #pragma unroll
  for (int nt=0; nt<8; nt++){
    int col = nt*16 + lr;
    float av = attn[r*128 + col];
    float bv = biasc[r*128 + col];
    int h = nt >> 1;
    #pragma unroll
    for (int i=0; i<4; i++){
      float x = acc[nt][i] + bv;
      x = (x > 0.f) ? x : 0.2f*x;
      sh[h][i] += x*av;
    }
  }
  #pragma unroll
  for (int h=0; h<NH; h++)
    #pragma unroll
    for (int i=0; i<4; i++){
      float v = sh[h][i];
      v += __shfl_xor(v, 1);
      v += __shfl_xor(v, 2);
      v += __shfl_xor(v, 4);
      v += __shfl_xor(v, 8);
      sh[h][i] = v;
    }
  if (lr == 0){
    #pragma unroll
    for (int i=0; i<4; i++){
      int m = w*16 + lq*4 + i;
      int e = eids[m];
      if (e >= 0){
        int pd = posD[e];
        float4 sv = { sh[0][i], sh[1][i], sh[2][i], sh[3][i] };
        *(float4*)&scoreD[(long long)pd*4] = sv;
      }
    }
  }
}

// ---- edge softmax over contiguous dst-sorted segments; 1 thread/node ----
// scoreD is transformed in place to exp(s - m); denom[node][4] written.
__global__ void k_softmax(const int* __restrict__ offD, float* __restrict__ scoreD,
                          float* __restrict__ denom, int N){
  int node = blockIdx.x*256 + threadIdx.x;
  if (node >= N) return;
  int s0 = offD[node], s1 = offD[node+1];
  if (s1 <= s0) return;
  float m0=-1e30f, m1=-1e30f, m2=-1e30f, m3=-1e30f;
  for (int j=s0; j<s1; j++){
    float4 sc = *(const float4*)&scoreD[(long long)j*4];
    m0=fmaxf(m0,sc.x); m1=fmaxf(m1,sc.y); m2=fmaxf(m2,sc.z); m3=fmaxf(m3,sc.w);
  }
  float d0=0.f,d1=0.f,d2=0.f,d3=0.f;
  for (int j=s0; j<s1; j++){
    float4 sc = *(const float4*)&scoreD[(long long)j*4];
    float4 ev = { __expf(sc.x-m0), __expf(sc.y-m1), __expf(sc.z-m2), __expf(sc.w-m3) };
    d0+=ev.x; d1+=ev.y; d2+=ev.z; d3+=ev.w;
    *(float4*)&scoreD[(long long)j*4] = ev;
  }
  float4 dv = { d0, d1, d2, d3 };
  *(float4*)&denom[(long long)node*4] = dv;
}

// ---- aggregation: wave per node, lane = feat dim; contiguous w + srcD ----
__global__ __launch_bounds__(256) void k_aggregate(
    const int* __restrict__ offD, const int* __restrict__ srcD,
    const float* __restrict__ wD, const float* __restrict__ denom,
    const u16* __restrict__ featb, float* __restrict__ out, int N){
  int node = blockIdx.x*4 + (threadIdx.x >> 6);
  int lane = threadIdx.x & 63;
  if (node >= N) return;
  int s0 = offD[node], s1 = offD[node+1];
  float a0=0.f, a1=0.f, a2=0.f, a3=0.f;
  #pragma unroll 2
  for (int j=s0; j<s1; ++j){
    int e = srcD[j];
    float4 wv = *(const float4*)&wD[(long long)j*4];
    float fv = b2f(featb[(long long)e*64 + lane]);
    a0 += wv.x*fv; a1 += wv.y*fv; a2 += wv.z*fv; a3 += wv.w*fv;
  }
  if (s1 > s0){
    float4 dv = *(const float4*)&denom[(long long)node*4];
    a0 *= 1.f/dv.x; a1 *= 1.f/dv.y; a2 *= 1.f/dv.z; a3 *= 1.f/dv.w;
  }
  float* op = out + (long long)node*256;
  op[lane]       = a0;
  op[64 + lane]  = a1;
  op[128 + lane] = a2;
  op[192 + lane] = a3;
}

extern "C" void kernel_launch(void* const* d_in, const int* in_sizes, int n_in,
                              void* d_out, int out_size, void* d_ws, size_t ws_size,
                              hipStream_t stream) {
  const float* feat  = (const float*)d_in[0];
  const float* qual  = (const float*)d_in[1];
  const float* wsrc  = (const float*)d_in[2];
  const float* bsrc  = (const float*)d_in[3];
  const float* wqual = (const float*)d_in[4];
  const float* bqual = (const float*)d_in[5];
  const float* attn  = (const float*)d_in[6];
  const int* src = (const int*)d_in[7];
  const int* dst = (const int*)d_in[8];
  const int* rt  = (const int*)d_in[9];
  const int* nid = (const int*)d_in[10];
  const int E = in_sizes[7];
  const int N = in_sizes[0] / 64;
  float* out = (float*)d_out;

  char* p = (char*)d_ws;
  auto alloc = [&](size_t bytes) -> void* {
    void* q = (void*)p;
    p += (bytes + 255) & ~(size_t)255;
    return q;
  };
  float* scoreD  = (float*)alloc((size_t)E*4*4);
  u16*  featb    = (u16*)  alloc((size_t)N*64*2);
  u16*  qualb    = (u16*)  alloc((size_t)N*64*2);
  u16*  Wt       = (u16*)  alloc((size_t)RELS*HDD*HDD*2);
  float* biasc   = (float*)alloc((size_t)RELS*HDD*4);
  int*  srcD     = (int*)  alloc((size_t)E*4);
  int*  posD     = (int*)  alloc((size_t)E*4);
  int*  permR    = (int*)  alloc((size_t)E*4);
  int*  offD     = (int*)  alloc((size_t)(N+1)*4);
  float* denom   = (float*)alloc((size_t)N*4*4);
  int*  bsums    = (int*)  alloc(4096);
  int*  bsums_sc = (int*)  alloc(4096);
  char* zbase = p;
  int*  deg      = (int*)  alloc((size_t)N*4);
  int*  curD     = (int*)  alloc((size_t)N*4);
  int*  rcnt     = (int*)  alloc(32);
  int*  roff     = (int*)  alloc(64);
  int*  rcur     = (int*)  alloc(32);
  size_t zbytes = (size_t)(p - zbase);

  hipMemsetAsync(zbase, 0, zbytes, stream);

  // prep
  {
    int totw = RELS*HDD*HDD + RELS*HDD;
    k_prep_w<<<(totw + 255)/256, 256, 0, stream>>>(wsrc, wqual, bsrc, bqual, Wt, biasc);
    int total = N*64;
    int nthr = (2*total)/8;
    k_prep_feat<<<(nthr + 255)/256, 256, 0, stream>>>(feat, qual, featb, qualb, total);
  }
  // histogram + scan + scatter
  int EB = (E + 255)/256;
  k_hist<<<EB, 256, 0, stream>>>(dst, rt, deg, rcnt, E);
  int NBLK = (N + 255)/256;
  k_scan_a<<<NBLK, 256, 0, stream>>>(deg, offD, bsums, N);
  k_scan_b<<<1, 512, 0, stream>>>(bsums, bsums_sc, offD, rcnt, roff, rcur, NBLK, N);
  k_scan_c<<<NBLK, 256, 0, stream>>>(offD, bsums_sc, N);
  k_scatter<<<EB, 256, 0, stream>>>(dst, rt, src, offD, curD, rcur, srcD, posD, permR, E);
  // fused score -> dst-sorted scoreD
  int NBS = (E + 63)/64 + RELS;
  k_score<<<NBS, 256, 0, stream>>>(featb, qualb, Wt, biasc, attn, src, nid, permR, roff, posD, scoreD);
  // softmax (in-place exp + denom), then aggregate
  k_softmax<<<(N + 255)/256, 256, 0, stream>>>(offD, scoreD, denom, N);
  k_aggregate<<<(N + 3)/4, 256, 0, stream>>>(offD, srcD, scoreD, denom, featb, out, N);
}

// Round 3
// 431.400 us; speedup vs baseline: 1.4619x; 1.0623x over previous
//
#include <hip/hip_runtime.h>
#include <hip/hip_bf16.h>

#define RELS 8
#define HDD 128
#define NH 4

typedef __attribute__((ext_vector_type(8))) short bf16x8;
typedef __attribute__((ext_vector_type(4))) float f32x4;
typedef unsigned short u16;

__device__ __forceinline__ u16 f2b(float v){
  union { float f; unsigned u; } x; x.f = v;
  unsigned r = x.u + 0x7fffu + ((x.u >> 16) & 1u);
  return (u16)(r >> 16);
}
__device__ __forceinline__ float b2f(u16 h){
  union { unsigned u; float f; } x; x.u = ((unsigned)h) << 16; return x.f;
}

// ---- prep: combined transposed weights (bf16) + combined bias ----
__global__ void k_prep_w(const float* __restrict__ wsrc, const float* __restrict__ wqual,
                         const float* __restrict__ bsrc, const float* __restrict__ bqual,
                         u16* __restrict__ Wt, float* __restrict__ biasc){
  int g = blockIdx.x*256 + threadIdx.x;
  if (g < RELS*HDD*HDD){
    int r = g >> 14, rem = g & 16383, n = rem >> 7, k = rem & 127;
    float v = (k < 64) ? wsrc[r*8192 + k*128 + n] : wqual[r*8192 + (k-64)*128 + n];
    Wt[g] = f2b(v);
  } else {
    int b = g - RELS*HDD*HDD;
    if (b < RELS*HDD) biasc[b] = bsrc[b] + bqual[b];
  }
}

// ---- prep: fp32 -> bf16 copies of feat and quality_emb ----
__global__ void k_prep_feat(const float* __restrict__ feat, const float* __restrict__ qual,
                            u16* __restrict__ featb, u16* __restrict__ qualb, int total){
  int g = (blockIdx.x*256 + threadIdx.x) * 8;
  const float* sp; u16* dp;
  if (g < total){ sp = feat; dp = featb; }
  else { g -= total; if (g >= total) return; sp = qual; dp = qualb; }
  float4 a = *(const float4*)(sp + g);
  float4 b = *(const float4*)(sp + g + 4);
  union { u16 h[8]; uint4 v; } o;
  o.h[0]=f2b(a.x); o.h[1]=f2b(a.y); o.h[2]=f2b(a.z); o.h[3]=f2b(a.w);
  o.h[4]=f2b(b.x); o.h[5]=f2b(b.y); o.h[6]=f2b(b.z); o.h[7]=f2b(b.w);
  *(uint4*)(dp + g) = o.v;
}

// ---- histograms: degree by dst, counts by relation ----
__global__ void k_hist(const int* __restrict__ dst, const int* __restrict__ rt,
                       int* __restrict__ deg, int* __restrict__ rcnt, int E){
  __shared__ int lh[RELS];
  int t = threadIdx.x;
  if (t < RELS) lh[t] = 0;
  __syncthreads();
  int e = blockIdx.x*256 + t;
  if (e < E){
    atomicAdd(&deg[dst[e]], 1);
    atomicAdd(&lh[rt[e]], 1);
  }
  __syncthreads();
  if (t < RELS && lh[t]) atomicAdd(&rcnt[t], lh[t]);
}

// ---- 3-phase exclusive scan over deg[N] -> offD ----
__global__ void k_scan_a(const int* __restrict__ deg, int* __restrict__ offD,
                         int* __restrict__ bsums, int N){
  __shared__ int s[256];
  int t = threadIdx.x, i = blockIdx.x*256 + t;
  int v = (i < N) ? deg[i] : 0;
  s[t] = v; __syncthreads();
  for (int off=1; off<256; off<<=1){
    int x = (t >= off) ? s[t-off] : 0;
    __syncthreads();
    s[t] += x;
    __syncthreads();
  }
  if (i < N) offD[i] = s[t] - v;
  if (t == 255) bsums[blockIdx.x] = s[255];
}

__global__ void k_scan_b(const int* __restrict__ bsums, int* __restrict__ bsums_sc,
                         int* __restrict__ offD, const int* __restrict__ rcnt,
                         int* __restrict__ roff, int* __restrict__ rcur,
                         int NBLK, int N){
  __shared__ int s[512];
  int t = threadIdx.x;
  int v = (t < NBLK) ? bsums[t] : 0;
  s[t] = v; __syncthreads();
  for (int off=1; off<512; off<<=1){
    int x = (t >= off) ? s[t-off] : 0;
    __syncthreads();
    s[t] += x;
    __syncthreads();
  }
  if (t < NBLK) bsums_sc[t] = s[t] - v;
  if (t == NBLK-1) offD[N] = s[t];
  if (t == 0){
    int a = 0;
    for (int r=0;r<RELS;r++){ roff[r]=a; rcur[r]=a; a += rcnt[r]; }
    roff[RELS] = a;
  }
}

__global__ void k_scan_c(int* __restrict__ offD, const int* __restrict__ bsums_sc, int N){
  int i = blockIdx.x*256 + threadIdx.x;
  if (i < N) offD[i] += bsums_sc[i >> 8];
}

// ---- scatter: dst-order srcD; rel-order srcR/nidR/posR (pre-gathered) ----
__global__ void k_scatter(const int* __restrict__ dst, const int* __restrict__ rt,
                          const int* __restrict__ src, const int* __restrict__ nid,
                          const int* __restrict__ offD, int* __restrict__ curD,
                          int* __restrict__ rcur,
                          int* __restrict__ srcD, int* __restrict__ srcR,
                          int* __restrict__ nidR, int* __restrict__ posR, int E){
  __shared__ int lh[RELS], lb[RELS];
  int t = threadIdx.x;
  if (t < RELS) lh[t] = 0;
  __syncthreads();
  int e = blockIdx.x*256 + t;
  int r = 0, rank = 0, pd = 0, sv = 0;
  if (e < E){
    int d = dst[e];
    sv = src[e];
    pd = offD[d] + atomicAdd(&curD[d], 1);
    srcD[pd] = sv;
    r = rt[e];
    rank = atomicAdd(&lh[r], 1);
  }
  __syncthreads();
  if (t < RELS && lh[t] > 0) lb[t] = atomicAdd(&rcur[t], lh[t]);
  __syncthreads();
  if (e < E){
    int pr = lb[r] + rank;
    srcR[pr] = sv;
    nidR[pr] = nid[e];
    posR[pr] = pd;
  }
}

// ---- fused projection + leaky_relu + attn dot -> scoreD[posR,4], MFMA ----
// B (head slice 128x32) held in per-wave VGPRs; As in LDS with XOR-swizzled
// 16B chunks (chunk ^= row&7) for conflict-free ds_read_b128.
__global__ __launch_bounds__(256) void k_score(
    const u16* __restrict__ featb, const u16* __restrict__ qualb,
    const u16* __restrict__ Wt, const float* __restrict__ biasc,
    const float* __restrict__ attn,
    const int* __restrict__ srcR, const int* __restrict__ nidR,
    const int* __restrict__ posR, const int* __restrict__ roff,
    float* __restrict__ scoreD){
  __shared__ u16 As[64*128];
  __shared__ int pos_s[64];
  __shared__ int sseg[3];
  int t = threadIdx.x;
  if (t == 0){
    int acc = 0, r = -1, base = 0, cnt = 0, bid = blockIdx.x;
    for (int rr=0; rr<RELS; rr++){
      int c = roff[rr+1] - roff[rr];
      int nb = (c + 63) >> 6;
      if (bid < acc + nb){
        int ch = bid - acc;
        r = rr; base = roff[rr] + ch*64; cnt = min(64, c - ch*64);
        break;
      }
      acc += nb;
    }
    sseg[0]=r; sseg[1]=base; sseg[2]=cnt;
  }
  __syncthreads();
  int r = sseg[0];
  if (r < 0) return;
  int base = sseg[1], cnt = sseg[2];

  // stage A: 64 edges x 128 bf16 (concat feat[srcR], qual[nidR]); 4 threads/edge
  int mloc = t >> 2, part = t & 3;
  uint4* As_v = (uint4*)As;
  if (mloc < cnt){
    if (part == 0) pos_s[mloc] = posR[base + mloc];
    const u16* rowp = (part < 2) ? (featb + (long long)srcR[base + mloc]*64)
                                 : (qualb + (long long)nidR[base + mloc]*64);
    const uint4* pv = (const uint4*)(rowp + (part & 1)*32);
    #pragma unroll
    for (int i=0;i<4;i++){
      int c = part*4 + i;
      As_v[mloc*16 + (c ^ (mloc & 7))] = pv[i];
    }
  } else {
    if (part == 0) pos_s[mloc] = -1;
    uint4 z = {0,0,0,0};
    #pragma unroll
    for (int i=0;i<4;i++){
      int c = part*4 + i;
      As_v[mloc*16 + (c ^ (mloc & 7))] = z;
    }
  }

  // per-wave B fragments: head w = t>>6, cols w*32 .. w*32+31
  int lane = t & 63, w = t >> 6;
  int lr = lane & 15, lq = lane >> 4;
  const u16* wbase = Wt + r*16384 + (w*32)*128;
  bf16x8 bfrag[2][4];
  #pragma unroll
  for (int nt=0; nt<2; nt++)
    #pragma unroll
    for (int kt=0; kt<4; kt++)
      bfrag[nt][kt] = *(const bf16x8*)(wbase + (nt*16 + lr)*128 + kt*32 + lq*8);

  __syncthreads();

  f32x4 acc[4][2];
  #pragma unroll
  for (int mt=0; mt<4; mt++){ acc[mt][0]=(f32x4){0,0,0,0}; acc[mt][1]=(f32x4){0,0,0,0}; }
  #pragma unroll
  for (int mt=0; mt<4; mt++){
    #pragma unroll
    for (int kt=0; kt<4; kt++){
      bf16x8 af = *(const bf16x8*)&As[(mt*16 + lr)*128 + (((kt*4 + lq) ^ (lr & 7))*8)];
      acc[mt][0] = __builtin_amdgcn_mfma_f32_16x16x32_bf16(af, bfrag[0][kt], acc[mt][0], 0, 0, 0);
      acc[mt][1] = __builtin_amdgcn_mfma_f32_16x16x32_bf16(af, bfrag[1][kt], acc[mt][1], 0, 0, 0);
    }
  }

  // epilogue: + bias, leaky_relu, * attn, reduce over the 32 cols of head w
  float sh[4][4];
  #pragma unroll
  for (int mt=0; mt<4; mt++)
    #pragma unroll
    for (int i=0; i<4; i++) sh[mt][i] = 0.f;
  #pragma unroll
  for (int nt=0; nt<2; nt++){
    int col = w*32 + nt*16 + lr;
    float av = attn[r*128 + col];
    float bv = biasc[r*128 + col];
    #pragma unroll
    for (int mt=0; mt<4; mt++)
      #pragma unroll
      for (int i=0; i<4; i++){
        float x = acc[mt][nt][i] + bv;
        x = (x > 0.f) ? x : 0.2f*x;
        sh[mt][i] += x*av;
      }
  }
  #pragma unroll
  for (int mt=0; mt<4; mt++)
    #pragma unroll
    for (int i=0; i<4; i++){
      float v = sh[mt][i];
      v += __shfl_xor(v, 1);
      v += __shfl_xor(v, 2);
      v += __shfl_xor(v, 4);
      v += __shfl_xor(v, 8);
      sh[mt][i] = v;
    }
  if (lr == 0){
    #pragma unroll
    for (int mt=0; mt<4; mt++)
      #pragma unroll
      for (int i=0; i<4; i++){
        int m = mt*16 + lq*4 + i;
        int pd = pos_s[m];
        if (pd >= 0) scoreD[(long long)pd*4 + w] = sh[mt][i];
      }
  }
}

// ---- edge softmax over contiguous dst-sorted segments; 1 thread/node ----
__global__ void k_softmax(const int* __restrict__ offD, float* __restrict__ scoreD,
                          float* __restrict__ denom, int N){
  int node = blockIdx.x*256 + threadIdx.x;
  if (node >= N) return;
  int s0 = offD[node], s1 = offD[node+1];
  if (s1 <= s0) return;
  float m0=-1e30f, m1=-1e30f, m2=-1e30f, m3=-1e30f;
  for (int j=s0; j<s1; j++){
    float4 sc = *(const float4*)&scoreD[(long long)j*4];
    m0=fmaxf(m0,sc.x); m1=fmaxf(m1,sc.y); m2=fmaxf(m2,sc.z); m3=fmaxf(m3,sc.w);
  }
  float d0=0.f,d1=0.f,d2=0.f,d3=0.f;
  for (int j=s0; j<s1; j++){
    float4 sc = *(const float4*)&scoreD[(long long)j*4];
    float4 ev = { __expf(sc.x-m0), __expf(sc.y-m1), __expf(sc.z-m2), __expf(sc.w-m3) };
    d0+=ev.x; d1+=ev.y; d2+=ev.z; d3+=ev.w;
    *(float4*)&scoreD[(long long)j*4] = ev;
  }
  float4 dv = { d0, d1, d2, d3 };
  *(float4*)&denom[(long long)node*4] = dv;
}

// ---- aggregation: wave per node, lane = feat dim; 4-wide MLP batching ----
__global__ __launch_bounds__(256) void k_aggregate(
    const int* __restrict__ offD, const int* __restrict__ srcD,
    const float* __restrict__ wD, const float* __restrict__ denom,
    const u16* __restrict__ featb, float* __restrict__ out, int N){
  int node = blockIdx.x*4 + (threadIdx.x >> 6);
  int lane = threadIdx.x & 63;
  if (node >= N) return;
  int s0 = offD[node], s1 = offD[node+1];
  float a0=0.f, a1=0.f, a2=0.f, a3=0.f;
  int j = s0;
  for (; j + 4 <= s1; j += 4){
    int e0 = srcD[j], e1 = srcD[j+1], e2 = srcD[j+2], e3 = srcD[j+3];
    float4 w0 = *(const float4*)&wD[(long long)j*4];
    float4 w1 = *(const float4*)&wD[(long long)(j+1)*4];
    float4 w2 = *(const float4*)&wD[(long long)(j+2)*4];
    float4 w3 = *(const float4*)&wD[(long long)(j+3)*4];
    float f0 = b2f(featb[(long long)e0*64 + lane]);
    float f1 = b2f(featb[(long long)e1*64 + lane]);
    float f2 = b2f(featb[(long long)e2*64 + lane]);
    float f3 = b2f(featb[(long long)e3*64 + lane]);
    a0 += w0.x*f0 + w1.x*f1 + w2.x*f2 + w3.x*f3;
    a1 += w0.y*f0 + w1.y*f1 + w2.y*f2 + w3.y*f3;
    a2 += w0.z*f0 + w1.z*f1 + w2.z*f2 + w3.z*f3;
    a3 += w0.w*f0 + w1.w*f1 + w2.w*f2 + w3.w*f3;
  }
  for (; j < s1; ++j){
    int e = srcD[j];
    float4 wv = *(const float4*)&wD[(long long)j*4];
    float fv = b2f(featb[(long long)e*64 + lane]);
    a0 += wv.x*fv; a1 += wv.y*fv; a2 += wv.z*fv; a3 += wv.w*fv;
  }
  if (s1 > s0){
    float4 dv = *(const float4*)&denom[(long long)node*4];
    a0 *= 1.f/dv.x; a1 *= 1.f/dv.y; a2 *= 1.f/dv.z; a3 *= 1.f/dv.w;
  }
  float* op = out + (long long)node*256;
  op[lane]       = a0;
  op[64 + lane]  = a1;
  op[128 + lane] = a2;
  op[192 + lane] = a3;
}

extern "C" void kernel_launch(void* const* d_in, const int* in_sizes, int n_in,
                              void* d_out, int out_size, void* d_ws, size_t ws_size,
                              hipStream_t stream) {
  const float* feat  = (const float*)d_in[0];
  const float* qual  = (const float*)d_in[1];
  const float* wsrc  = (const float*)d_in[2];
  const float* bsrc  = (const float*)d_in[3];
  const float* wqual = (const float*)d_in[4];
  const float* bqual = (const float*)d_in[5];
  const float* attn  = (const float*)d_in[6];
  const int* src = (const int*)d_in[7];
  const int* dst = (const int*)d_in[8];
  const int* rt  = (const int*)d_in[9];
  const int* nid = (const int*)d_in[10];
  const int E = in_sizes[7];
  const int N = in_sizes[0] / 64;
  float* out = (float*)d_out;

  char* p = (char*)d_ws;
  auto alloc = [&](size_t bytes) -> void* {
    void* q = (void*)p;
    p += (bytes + 255) & ~(size_t)255;
    return q;
  };
  float* scoreD  = (float*)alloc((size_t)E*4*4);
  u16*  featb    = (u16*)  alloc((size_t)N*64*2);
  u16*  qualb    = (u16*)  alloc((size_t)N*64*2);
  u16*  Wt       = (u16*)  alloc((size_t)RELS*HDD*HDD*2);
  float* biasc   = (float*)alloc((size_t)RELS*HDD*4);
  int*  srcD     = (int*)  alloc((size_t)E*4);
  int*  srcR     = (int*)  alloc((size_t)E*4);
  int*  nidR     = (int*)  alloc((size_t)E*4);
  int*  posR     = (int*)  alloc((size_t)E*4);
  int*  offD     = (int*)  alloc((size_t)(N+1)*4);
  float* denom   = (float*)alloc((size_t)N*4*4);
  int*  bsums    = (int*)  alloc(4096);
  int*  bsums_sc = (int*)  alloc(4096);
  char* zbase = p;
  int*  deg      = (int*)  alloc((size_t)N*4);
  int*  curD     = (int*)  alloc((size_t)N*4);
  int*  rcnt     = (int*)  alloc(32);
  int*  roff     = (int*)  alloc(64);
  int*  rcur     = (int*)  alloc(32);
  size_t zbytes = (size_t)(p - zbase);

  hipMemsetAsync(zbase, 0, zbytes, stream);

  // prep
  {
    int totw = RELS*HDD*HDD + RELS*HDD;
    k_prep_w<<<(totw + 255)/256, 256, 0, stream>>>(wsrc, wqual, bsrc, bqual, Wt, biasc);
    int total = N*64;
    int nthr = (2*total)/8;
    k_prep_feat<<<(nthr + 255)/256, 256, 0, stream>>>(feat, qual, featb, qualb, total);
  }
  // histogram + scan + scatter
  int EB = (E + 255)/256;
  k_hist<<<EB, 256, 0, stream>>>(dst, rt, deg, rcnt, E);
  int NBLK = (N + 255)/256;
  k_scan_a<<<NBLK, 256, 0, stream>>>(deg, offD, bsums, N);
  k_scan_b<<<1, 512, 0, stream>>>(bsums, bsums_sc, offD, rcnt, roff, rcur, NBLK, N);
  k_scan_c<<<NBLK, 256, 0, stream>>>(offD, bsums_sc, N);
  k_scatter<<<EB, 256, 0, stream>>>(dst, rt, src, nid, offD, curD, rcur, srcD, srcR, nidR, posR, E);
  // fused score -> dst-sorted scoreD
  int NBS = (E + 63)/64 + RELS;
  k_score<<<NBS, 256, 0, stream>>>(featb, qualb, Wt, biasc, attn, srcR, nidR, posR, roff, scoreD);
  // softmax (in-place exp + denom), then aggregate
  k_softmax<<<(N + 255)/256, 256, 0, stream>>>(offD, scoreD, denom, N);
  k_aggregate<<<(N + 3)/4, 256, 0, stream>>>(offD, srcD, scoreD, denom, featb, out, N);
}